// Round 10
// baseline (617.896 us; speedup 1.0000x reference)
//
#include <hip/hip_runtime.h>
#include <hip/hip_bf16.h>
#include <math.h>

#define SEQ_LEN 8192
#define LAT 64
#define NPOS 8256          // SEQ_LEN + LAT
#define NBATCH 16
#define NHEADS 8
#define DH 64
#define DIM 512
#define NBH 128            // NBATCH*NHEADS
#define NROWS 132096       // NBATCH*NPOS = 2064*64
#define NCHUNK 4
#define NTILES 129         // NPOS/64
#define TPC 33             // tiles per chunk (4*33=132 >= 129)

typedef unsigned short u16;
typedef unsigned int   u32;
using short8 = __attribute__((ext_vector_type(8))) short;  // MFMA bf16 A/B frag
using f32x4  = __attribute__((ext_vector_type(4))) float;  // MFMA C/D frag

static __device__ __forceinline__ float bf2f(u16 u) {
  union { u32 i; float f; } v; v.i = ((u32)u) << 16; return v.f;
}
static __device__ __forceinline__ u16 f2bf(float f) {  // round-to-nearest-even (manual, known-good)
  union { float f; u32 i; } v; v.f = f;
  u32 x = v.i;
  return (u16)((x + 0x7fffu + ((x >> 16) & 1u)) >> 16);
}

// ---------------- kernel 0: rope tables ----------------
__global__ void k_rtable(float* __restrict__ ctab, float* __restrict__ stab) {
  int idx = blockIdx.x * 256 + threadIdx.x;   // NPOS*32 total
  int pos = idx >> 5, i = idx & 31;
  float inv = (float)(1.0 / pow(10000.0, (double)(2 * i) / 64.0));
  float ang = (float)pos * inv;
  ctab[idx] = cosf(ang);
  stab[idx] = sinf(ang);
}

// ---------------- kernel 0b: cast wkv to bf16 ----------------
__global__ __launch_bounds__(256) void k_wcast(const float* __restrict__ wkv, u16* __restrict__ wbf) {
  size_t i = (size_t)blockIdx.x * 256 + threadIdx.x;   // DIM*DIM/8 iters
  const float4* src = (const float4*)wkv;
  float4 a = src[2 * i], b = src[2 * i + 1];
  uint4 o;
  o.x = (u32)f2bf(a.x) | ((u32)f2bf(a.y) << 16);
  o.y = (u32)f2bf(a.z) | ((u32)f2bf(a.w) << 16);
  o.z = (u32)f2bf(b.x) | ((u32)f2bf(b.y) << 16);
  o.w = (u32)f2bf(b.z) | ((u32)f2bf(b.w) << 16);
  ((uint4*)wbf)[i] = o;
}

// ---------------- kernel 1: q projection (latent rows only) + rope + scale ----------------
__global__ __launch_bounds__(256) void k_qproj(
    const float* __restrict__ x, const float* __restrict__ wq,
    const float* __restrict__ ctab, const float* __restrict__ stab,
    u16* __restrict__ qws) {
  __shared__ __align__(16) float xs[8 * 512];
  int t = threadIdx.x;
  int lr0 = blockIdx.x * 8;
  int batch = lr0 >> 6;
  int lat0 = lr0 & 63;
  for (int u = 0; u < 4; ++u) {
    int e = u * 256 + t;
    int row = e >> 7, c4 = e & 127;
    size_t m = (size_t)batch * NPOS + SEQ_LEN + lat0 + row;
    ((float4*)xs)[e] = ((const float4*)(x + m * DIM))[c4];
  }
  __syncthreads();
  float acc0[8], acc1[8];
#pragma unroll
  for (int r = 0; r < 8; ++r) { acc0[r] = 0.f; acc1[r] = 0.f; }
  const float4* w0 = (const float4*)(wq + (size_t)t * DIM);
  const float4* w1 = (const float4*)(wq + (size_t)(t + 256) * DIM);
  for (int kk = 0; kk < 128; ++kk) {
    float4 a = w0[kk], b = w1[kk];
#pragma unroll
    for (int r = 0; r < 8; ++r) {
      float4 xv = ((const float4*)xs)[r * 128 + kk];
      acc0[r] = fmaf(a.x, xv.x, fmaf(a.y, xv.y, fmaf(a.z, xv.z, fmaf(a.w, xv.w, acc0[r]))));
      acc1[r] = fmaf(b.x, xv.x, fmaf(b.y, xv.y, fmaf(b.z, xv.z, fmaf(b.w, xv.w, acc1[r]))));
    }
  }
  __syncthreads();
#pragma unroll
  for (int r = 0; r < 8; ++r) { xs[r * 512 + t] = acc0[r]; xs[r * 512 + t + 256] = acc1[r]; }
  __syncthreads();
  int rh = t >> 2, sub = t & 3;
  int row = rh >> 3, head = rh & 7;
  int lat = lat0 + row, pos = SEQ_LEN + lat;
  int bh = batch * 8 + head;
  u16* qd = qws + ((size_t)bh * LAT + lat) * DH;
#pragma unroll
  for (int u = 0; u < 8; ++u) {
    int i = sub * 8 + u;
    float v1 = xs[row * 512 + head * 64 + i];
    float v2 = xs[row * 512 + head * 64 + i + 32];
    float cc = ctab[pos * 32 + i], ss = stab[pos * 32 + i];
    qd[i]      = f2bf((v1 * cc - v2 * ss) * 0.125f);
    qd[i + 32] = f2bf((v2 * cc + v1 * ss) * 0.125f);
  }
}

// ---------------- kernel 2: kv GEMM, wave-independent, NO LDS / NO barriers ----------------
// Grid 4128 x 256thr. Block = (m-tile of 64 rows) x (n-half of 256); wave w owns 64x64 tile
// at n0 = nhalf*256 + w*64 (exactly one head). A frags: f32 direct from x + in-reg cvt.
// B frags: bf16 direct from L2-resident wbf (k_attn's proven QK^T load pattern).
// Epilogue: rope pairs lane-local (acc[nt] vs acc[nt+2]); LN row-reduce via 4 shfl_xor (c-bits).
__global__ __launch_bounds__(256, 3) void k_kvgemm(
    const float* __restrict__ x, const u16* __restrict__ wbf,
    const float* __restrict__ ctab, const float* __restrict__ stab,
    u16* __restrict__ kvws, float2* __restrict__ stats) {
  const int t = threadIdx.x;
  const int lane = t & 63, w = t >> 6;
  const int c = lane & 15, g = lane >> 4;
  // bijective XCD swizzle (4128 = 8*516); consecutive s pairs the two n-halves of an m-tile
  const int s = (blockIdx.x & 7) * 516 + (blockIdx.x >> 3);
  const int mtile = s >> 1, nhalf = s & 1;
  const size_t m0 = (size_t)mtile * 64;
  const int n0 = nhalf * 256 + w * 64;          // this wave's head*64
  const int b = mtile / 129;                    // 129 m-tiles per batch (8256/64)
  const int pos0 = (mtile % 129) * 64;

  f32x4 acc[4][4];
#pragma unroll
  for (int mt = 0; mt < 4; ++mt)
#pragma unroll
    for (int nt = 0; nt < 4; ++nt) acc[mt][nt] = (f32x4){0.f, 0.f, 0.f, 0.f};

  const float* a0p = x + (m0 + c) * DIM + g * 8;          // row m0+mt*16+c, k-window g*8
  const u16*   b0p = wbf + (size_t)(n0 + c) * DIM + g * 8;

#pragma unroll 4
  for (int ks = 0; ks < 16; ++ks) {             // K = 16 * 32
    const int ko = ks * 32;
    short8 bn[4];
#pragma unroll
    for (int nt = 0; nt < 4; ++nt)
      bn[nt] = *(const short8*)(b0p + (size_t)nt * 16 * DIM + ko);
    short8 am[4];
#pragma unroll
    for (int mt = 0; mt < 4; ++mt) {
      const float* ap = a0p + (size_t)mt * 16 * DIM + ko;
      float4 lo = *(const float4*)ap;
      float4 hi = *(const float4*)(ap + 4);
      short8 o;
      o[0] = (short)__bfloat16_as_ushort(__float2bfloat16(lo.x));
      o[1] = (short)__bfloat16_as_ushort(__float2bfloat16(lo.y));
      o[2] = (short)__bfloat16_as_ushort(__float2bfloat16(lo.z));
      o[3] = (short)__bfloat16_as_ushort(__float2bfloat16(lo.w));
      o[4] = (short)__bfloat16_as_ushort(__float2bfloat16(hi.x));
      o[5] = (short)__bfloat16_as_ushort(__float2bfloat16(hi.y));
      o[6] = (short)__bfloat16_as_ushort(__float2bfloat16(hi.z));
      o[7] = (short)__bfloat16_as_ushort(__float2bfloat16(hi.w));
      am[mt] = o;
    }
#pragma unroll
    for (int mt = 0; mt < 4; ++mt)
#pragma unroll
      for (int nt = 0; nt < 4; ++nt)
        acc[mt][nt] = __builtin_amdgcn_mfma_f32_16x16x32_bf16(am[mt], bn[nt], acc[mt][nt], 0, 0, 0);
  }

  // epilogue: per (mt, r) this lane holds row (mt*16+4g+r), head-dims {nt*16+c}
  const int head = n0 >> 6;
  const int bh = b * 8 + head;
#pragma unroll
  for (int mt = 0; mt < 4; ++mt) {
#pragma unroll
    for (int r = 0; r < 4; ++r) {
      const int row = mt * 16 + 4 * g + r;
      const int pos = pos0 + row;
      // rope: dd = nt*16+c (nt 0,1) pairs with dd+32 (nt+2); i = dd
      float cc0 = ctab[pos * 32 + c],      ss0 = stab[pos * 32 + c];
      float cc1 = ctab[pos * 32 + 16 + c], ss1 = stab[pos * 32 + 16 + c];
      float v1a = acc[mt][0][r], v2a = acc[mt][2][r];
      float v1b = acc[mt][1][r], v2b = acc[mt][3][r];
      float o0 = v1a * cc0 - v2a * ss0;
      float o2 = v2a * cc0 + v1a * ss0;
      float o1 = v1b * cc1 - v2b * ss1;
      float o3 = v2b * cc1 + v1b * ss1;
      float sum = (o0 + o1) + (o2 + o3);
      sum += __shfl_xor(sum, 1); sum += __shfl_xor(sum, 2);
      sum += __shfl_xor(sum, 4); sum += __shfl_xor(sum, 8);
      float mu = sum * 0.015625f;
      float d0 = o0 - mu, d1 = o1 - mu, d2 = o2 - mu, d3 = o3 - mu;
      float sq = fmaf(d0, d0, fmaf(d1, d1, fmaf(d2, d2, d3 * d3)));
      sq += __shfl_xor(sq, 1); sq += __shfl_xor(sq, 2);
      sq += __shfl_xor(sq, 4); sq += __shfl_xor(sq, 8);
      float rstd = rsqrtf(sq * 0.015625f + 1e-5f);
      u16* kvp = kvws + ((size_t)bh * NPOS + pos) * DH;
      kvp[c]      = f2bf(o0);
      kvp[16 + c] = f2bf(o1);
      kvp[32 + c] = f2bf(o2);
      kvp[48 + c] = f2bf(o3);
      if (c == 0) stats[(size_t)bh * NPOS + pos] = make_float2(mu, rstd);
    }
  }
}

// ---------------- kernel 3: flash attention, LN folded out of PV (4 chunks) ----------------
// out_d = (g_d*(O_d - Q2) + b_d*L)/L with O = sum p*rstd*kv, Q2 = sum p*mu*rstd, L = sum p.
__global__ __launch_bounds__(256) void k_attn(
    const u16* __restrict__ qws, const u16* __restrict__ kvws,
    const float2* __restrict__ stats,
    float* __restrict__ pout, float* __restrict__ pml) {
  __shared__ __align__(16) u16 LT[64 * 64];        // raw kv^T [dd][j], rows XOR-swizzled
  __shared__ __align__(16) u16 Pl[4][16 * 64];     // per-wave P' [i][j], XOR-swizzled
  int t = threadIdx.x;
  int lane = t & 63, w = t >> 6;
  int c = lane & 15, g = lane >> 4;
  int bh = blockIdx.y, chunk = blockIdx.x;
  int tt0 = chunk * TPC;
  int tt1 = tt0 + TPC; if (tt1 > NTILES) tt1 = NTILES;
  short8 qa[2];
  {
    const u16* qrow = qws + ((size_t)bh * LAT + w * 16 + c) * DH;
    qa[0] = *(const short8*)(qrow + 8 * g);
    qa[1] = *(const short8*)(qrow + 32 + 8 * g);
  }
  f32x4 oacc[4];
#pragma unroll
  for (int nt = 0; nt < 4; ++nt) oacc[nt] = (f32x4){0.f, 0.f, 0.f, 0.f};
  float m_run[4], l_run[4], q2_run[4];
#pragma unroll
  for (int r = 0; r < 4; ++r) { m_run[r] = -INFINITY; l_run[r] = 0.f; q2_run[r] = 0.f; }
  int sj = t & 63, sw = t >> 6;
  for (int tt = tt0; tt < tt1; ++tt) {
    int j0 = tt * 64;
    __syncthreads();
    {                                               // pure transpose staging: LT[dd][j] = kv[j][dd]
      const u16* src = kvws + ((size_t)bh * NPOS + j0 + sj) * DH + 16 * sw;
      short8 v0 = *(const short8*)src;
      short8 v1 = *(const short8*)(src + 8);
      char* ltb = (char*)LT;
#pragma unroll
      for (int e = 0; e < 16; ++e) {
        int dd = 16 * sw + e;
        u16 uv = (u16)((e < 8) ? v0[e] : v1[e - 8]);
        *(u16*)(ltb + dd * 128 + ((2 * sj) ^ ((dd & 7) << 4))) = uv;
      }
    }
    __syncthreads();
    f32x4 sacc[4];
#pragma unroll
    for (int jn = 0; jn < 4; ++jn) sacc[jn] = (f32x4){0.f, 0.f, 0.f, 0.f};
    const u16* kb = kvws + ((size_t)bh * NPOS + j0) * DH;
#pragma unroll
    for (int ks = 0; ks < 2; ++ks)
#pragma unroll
      for (int jn = 0; jn < 4; ++jn) {
        short8 kf = *(const short8*)(kb + (size_t)(jn * 16 + c) * DH + ks * 32 + 8 * g);
        sacc[jn] = __builtin_amdgcn_mfma_f32_16x16x32_bf16(qa[ks], kf, sacc[jn], 0, 0, 0);
      }
    float rsd[4], musig[4];
#pragma unroll
    for (int jn = 0; jn < 4; ++jn) {
      float2 sv = stats[(size_t)bh * NPOS + j0 + jn * 16 + c];
      rsd[jn] = sv.y; musig[jn] = sv.x * sv.y;
    }
    char* pb = (char*)Pl[w];
#pragma unroll
    for (int r = 0; r < 4; ++r) {
      float mt0 = fmaxf(fmaxf(sacc[0][r], sacc[1][r]), fmaxf(sacc[2][r], sacc[3][r]));
      mt0 = fmaxf(mt0, __shfl_xor(mt0, 1));
      mt0 = fmaxf(mt0, __shfl_xor(mt0, 2));
      mt0 = fmaxf(mt0, __shfl_xor(mt0, 4));
      mt0 = fmaxf(mt0, __shfl_xor(mt0, 8));
      float mnew = fmaxf(m_run[r], mt0);
      float corr = __expf(m_run[r] - mnew);
      m_run[r] = mnew;
      float ts = 0.f, tq = 0.f;
#pragma unroll
      for (int jn = 0; jn < 4; ++jn) {
        float p = __expf(sacc[jn][r] - mnew);
        ts += p;
        tq = fmaf(p, musig[jn], tq);
        sacc[jn][r] = p * rsd[jn];              // P' = p * rstd_j
      }
      ts += __shfl_xor(ts, 1); ts += __shfl_xor(ts, 2);
      ts += __shfl_xor(ts, 4); ts += __shfl_xor(ts, 8);
      tq += __shfl_xor(tq, 1); tq += __shfl_xor(tq, 2);
      tq += __shfl_xor(tq, 4); tq += __shfl_xor(tq, 8);
      l_run[r]  = l_run[r]  * corr + ts;
      q2_run[r] = q2_run[r] * corr + tq;
#pragma unroll
      for (int nt = 0; nt < 4; ++nt) oacc[nt][r] *= corr;
      int i = 4 * g + r;
      int isw = (i & 7) << 4;
#pragma unroll
      for (int jn = 0; jn < 4; ++jn) {
        int j = jn * 16 + c;
        *(u16*)(pb + i * 128 + ((2 * j) ^ isw)) = f2bf(sacc[jn][r]);
      }
    }
#pragma unroll
    for (int ks = 0; ks < 2; ++ks) {
      short8 pa = *(const short8*)(pb + c * 128 + ((ks * 64 + 16 * g) ^ ((c & 7) << 4)));
#pragma unroll
      for (int nt = 0; nt < 4; ++nt) {
        int dd = nt * 16 + c;
        short8 lv = *(const short8*)((char*)LT + dd * 128 + ((ks * 64 + 16 * g) ^ ((dd & 7) << 4)));
        oacc[nt] = __builtin_amdgcn_mfma_f32_16x16x32_bf16(pa, lv, oacc[nt], 0, 0, 0);
      }
    }
  }
  size_t ob = (size_t)bh * NCHUNK + chunk;
#pragma unroll
  for (int nt = 0; nt < 4; ++nt)
#pragma unroll
    for (int r = 0; r < 4; ++r) {
      int i = w * 16 + 4 * g + r;
      pout[(ob * 64 + i) * 64 + nt * 16 + c] = oacc[nt][r];
    }
  if (c == 0) {
#pragma unroll
    for (int r = 0; r < 4; ++r) {
      int i = w * 16 + 4 * g + r;
      pml[(ob * 3 + 0) * 64 + i] = m_run[r];
      pml[(ob * 3 + 1) * 64 + i] = l_run[r];
      pml[(ob * 3 + 2) * 64 + i] = q2_run[r];
    }
  }
}

// ---------------- kernel 4: combine chunks, apply LN gamma/beta, permute to output ----------------
__global__ __launch_bounds__(256) void k_combine(
    const float* __restrict__ pout, const float* __restrict__ pml,
    const float* __restrict__ lng, const float* __restrict__ lnb,
    float* __restrict__ out) {
  int bh = blockIdx.x, t = threadIdx.x;
  int i = t >> 2, dq = t & 3;
  float mv[NCHUNK], lv[NCHUNK], qv[NCHUNK];
#pragma unroll
  for (int cc = 0; cc < NCHUNK; ++cc) {
    size_t ob = (size_t)bh * NCHUNK + cc;
    mv[cc] = pml[(ob * 3 + 0) * 64 + i];
    lv[cc] = pml[(ob * 3 + 1) * 64 + i];
    qv[cc] = pml[(ob * 3 + 2) * 64 + i];
  }
  float M = -INFINITY;
#pragma unroll
  for (int cc = 0; cc < NCHUNK; ++cc) M = fmaxf(M, mv[cc]);
  float L = 0.f, Q2 = 0.f, wcf[NCHUNK];
#pragma unroll
  for (int cc = 0; cc < NCHUNK; ++cc) {
    wcf[cc] = __expf(mv[cc] - M);
    L = fmaf(wcf[cc], lv[cc], L);
    Q2 = fmaf(wcf[cc], qv[cc], Q2);
  }
  float invL = 1.0f / L;
#pragma unroll
  for (int e = 0; e < 16; ++e) {
    int dd = dq * 16 + e;
    float O = 0.f;
#pragma unroll
    for (int cc = 0; cc < NCHUNK; ++cc)
      O = fmaf(wcf[cc], pout[(((size_t)bh * NCHUNK + cc) * 64 + i) * 64 + dd], O);
    float val = (lng[dd] * (O - Q2) + lnb[dd] * L) * invL;
    out[((size_t)(bh >> 3) * LAT + i) * DIM + (bh & 7) * DH + dd] = val;
  }
}

extern "C" void kernel_launch(void* const* d_in, const int* in_sizes, int n_in,
                              void* d_out, int out_size, void* d_ws, size_t ws_size,
                              hipStream_t stream) {
  const float* x   = (const float*)d_in[0];
  const float* wq  = (const float*)d_in[1];
  const float* wkv = (const float*)d_in[2];
  const float* lng = (const float*)d_in[3];
  const float* lnb = (const float*)d_in[4];
  float* out = (float*)d_out;
  char* ws = (char*)d_ws;
  size_t off = 0;
  auto alloc = [&](size_t bytes) { char* p = ws + off; off += (bytes + 255) & ~(size_t)255; return p; };
  float*  ctab  = (float*)alloc((size_t)NPOS * 32 * 4);
  float*  stab  = (float*)alloc((size_t)NPOS * 32 * 4);
  u16*    qws   = (u16*)alloc((size_t)NBH * LAT * DH * 2);
  u16*    kvws  = (u16*)alloc((size_t)NBH * NPOS * DH * 2);
  float2* stats = (float2*)alloc((size_t)NBH * NPOS * 8);
  float*  pout  = (float*)alloc((size_t)NBH * NCHUNK * 64 * 64 * 4);
  float*  pml   = (float*)alloc((size_t)NBH * NCHUNK * 3 * 64 * 4);
  u16*    wbf   = (u16*)alloc((size_t)DIM * DIM * 2);
  (void)in_sizes; (void)n_in; (void)out_size; (void)ws_size;

  hipLaunchKernelGGL(k_rtable, dim3(NPOS * 32 / 256), dim3(256), 0, stream, ctab, stab);
  hipLaunchKernelGGL(k_wcast, dim3(DIM * DIM / 8 / 256), dim3(256), 0, stream, wkv, wbf);
  hipLaunchKernelGGL(k_qproj, dim3(128), dim3(256), 0, stream, x, wq, ctab, stab, qws);
  hipLaunchKernelGGL(k_kvgemm, dim3(4128), dim3(256), 0, stream, x, wbf, ctab, stab, kvws, stats);
  hipLaunchKernelGGL(k_attn, dim3(NCHUNK, NBH), dim3(256), 0, stream, qws, kvws, stats, pout, pml);
  hipLaunchKernelGGL(k_combine, dim3(NBH), dim3(256), 0, stream, pout, pml, lng, lnb, out);
}

// Round 12
// 513.150 us; speedup vs baseline: 1.2041x; 1.2041x over previous
//
#include <hip/hip_runtime.h>
#include <hip/hip_bf16.h>
#include <math.h>

#define SEQ_LEN 8192
#define LAT 64
#define NPOS 8256          // SEQ_LEN + LAT
#define NBATCH 16
#define NHEADS 8
#define DH 64
#define DIM 512
#define NBH 128            // NBATCH*NHEADS
#define NROWS 132096       // NBATCH*NPOS = 1032*128
#define NCHUNK 4
#define NTILES 129         // NPOS/64
#define TPC 33             // tiles per chunk (4*33=132 >= 129)

typedef unsigned short u16;
typedef unsigned int   u32;
using short8 = __attribute__((ext_vector_type(8))) short;  // MFMA bf16 A/B frag
using f32x4  = __attribute__((ext_vector_type(4))) float;  // MFMA C/D frag

static __device__ __forceinline__ float bf2f(u16 u) {
  union { u32 i; float f; } v; v.i = ((u32)u) << 16; return v.f;
}
static __device__ __forceinline__ u16 f2bf(float f) {  // round-to-nearest-even (manual, known-good)
  union { float f; u32 i; } v; v.f = f;
  u32 x = v.i;
  return (u16)((x + 0x7fffu + ((x >> 16) & 1u)) >> 16);
}
static __device__ __forceinline__ void gload_lds16(const void* g, void* l) {
  __builtin_amdgcn_global_load_lds(
      (const __attribute__((address_space(1))) unsigned int*)g,
      (__attribute__((address_space(3))) unsigned int*)l, 16, 0, 0);
}

// ---------------- kernel 0: rope tables ----------------
__global__ void k_rtable(float* __restrict__ ctab, float* __restrict__ stab) {
  int idx = blockIdx.x * 256 + threadIdx.x;   // NPOS*32 total
  int pos = idx >> 5, i = idx & 31;
  float inv = (float)(1.0 / pow(10000.0, (double)(2 * i) / 64.0));
  float ang = (float)pos * inv;
  ctab[idx] = cosf(ang);
  stab[idx] = sinf(ang);
}

// ---------------- kernel 0b: cast wkv to bf16 ----------------
__global__ __launch_bounds__(256) void k_wcast(const float* __restrict__ wkv, u16* __restrict__ wbf) {
  size_t i = (size_t)blockIdx.x * 256 + threadIdx.x;   // DIM*DIM/8 iters
  const float4* src = (const float4*)wkv;
  float4 a = src[2 * i], b = src[2 * i + 1];
  uint4 o;
  o.x = (u32)f2bf(a.x) | ((u32)f2bf(a.y) << 16);
  o.y = (u32)f2bf(a.z) | ((u32)f2bf(a.w) << 16);
  o.z = (u32)f2bf(b.x) | ((u32)f2bf(b.y) << 16);
  o.w = (u32)f2bf(b.z) | ((u32)f2bf(b.w) << 16);
  ((uint4*)wbf)[i] = o;
}

// ---------------- kernel 1: q projection (latent rows only) + rope + scale ----------------
__global__ __launch_bounds__(256) void k_qproj(
    const float* __restrict__ x, const float* __restrict__ wq,
    const float* __restrict__ ctab, const float* __restrict__ stab,
    u16* __restrict__ qws) {
  __shared__ __align__(16) float xs[8 * 512];
  int t = threadIdx.x;
  int lr0 = blockIdx.x * 8;
  int batch = lr0 >> 6;
  int lat0 = lr0 & 63;
  for (int u = 0; u < 4; ++u) {
    int e = u * 256 + t;
    int row = e >> 7, c4 = e & 127;
    size_t m = (size_t)batch * NPOS + SEQ_LEN + lat0 + row;
    ((float4*)xs)[e] = ((const float4*)(x + m * DIM))[c4];
  }
  __syncthreads();
  float acc0[8], acc1[8];
#pragma unroll
  for (int r = 0; r < 8; ++r) { acc0[r] = 0.f; acc1[r] = 0.f; }
  const float4* w0 = (const float4*)(wq + (size_t)t * DIM);
  const float4* w1 = (const float4*)(wq + (size_t)(t + 256) * DIM);
  for (int kk = 0; kk < 128; ++kk) {
    float4 a = w0[kk], b = w1[kk];
#pragma unroll
    for (int r = 0; r < 8; ++r) {
      float4 xv = ((const float4*)xs)[r * 128 + kk];
      acc0[r] = fmaf(a.x, xv.x, fmaf(a.y, xv.y, fmaf(a.z, xv.z, fmaf(a.w, xv.w, acc0[r]))));
      acc1[r] = fmaf(b.x, xv.x, fmaf(b.y, xv.y, fmaf(b.z, xv.z, fmaf(b.w, xv.w, acc1[r]))));
    }
  }
  __syncthreads();
#pragma unroll
  for (int r = 0; r < 8; ++r) { xs[r * 512 + t] = acc0[r]; xs[r * 512 + t + 256] = acc1[r]; }
  __syncthreads();
  int rh = t >> 2, sub = t & 3;
  int row = rh >> 3, head = rh & 7;
  int lat = lat0 + row, pos = SEQ_LEN + lat;
  int bh = batch * 8 + head;
  u16* qd = qws + ((size_t)bh * LAT + lat) * DH;
#pragma unroll
  for (int u = 0; u < 8; ++u) {
    int i = sub * 8 + u;
    float v1 = xs[row * 512 + head * 64 + i];
    float v2 = xs[row * 512 + head * 64 + i + 32];
    float cc = ctab[pos * 32 + i], ss = stab[pos * 32 + i];
    qd[i]      = f2bf((v1 * cc - v2 * ss) * 0.125f);
    qd[i + 32] = f2bf((v2 * cc + v1 * ss) * 0.125f);
  }
}

// ---------------- kernel 2: persistent kv GEMM, raw barriers + counted vmcnt (T4) ----------------
// 512 blocks x 256 thr (2 blocks/CU, 80KB LDS). Block: fixed n0 (128 of 512), ~8 m-panels.
// Per K-step: issueB(kt+1) gload_lds (4 ops), issueA(kt+2) f32 reg loads (8 ops),
// MFMA(kt), cvt+ds_write A(kt+1), s_waitcnt vmcnt(8) (drain B only, keep A(kt+2) in flight),
// raw s_barrier. Epilogue: 4 passes via 16KB swizzled Cs (rope+LN stats), plain __syncthreads.
// Structure executed successfully in R6; numerics fixed (manual RNE + subtract-mean variance).
__global__ __launch_bounds__(256, 2) void k_kvgemm(
    const float* __restrict__ x, const u16* __restrict__ wbf,
    const float* __restrict__ ctab, const float* __restrict__ stab,
    u16* __restrict__ kvws, float2* __restrict__ stats) {
  __shared__ __align__(16) char smem[81920];
  // [0,16K) Abuf0 | [16K,32K) Abuf1 | [32K,48K) Bbuf0 | [48K,64K) Bbuf1 | [64K,80K) Cs[32][128] f32 swz
  float* Cs = (float*)(smem + 65536);
  const int t = threadIdx.x;
  const int lane = t & 63, w = t >> 6;
  const int wm = w >> 1, wn = w & 1;          // 2x2 waves, wave tile 64x64
  const int c = lane & 15, g = lane >> 4;
  const int cs7 = (c & 7) << 4;               // frag-read swizzle (row&7 == c&7)
  const int bid = blockIdx.x;
  const int q = bid >> 3;                     // 0..63
  const int n0 = (q & 3) * 128;
  const int pair = (bid & 7) * 16 + (q >> 2); // 0..127; 4 sibling n-blocks share same XCD + panels
  const int arow = t >> 1, hs = t & 1;
  const int asw = (arow & 7) << 4;
  const int rB = t >> 3;
  const int c16s = (t & 7) ^ (rB & 7);
  const u16* bsrc = wbf + (size_t)(n0 + rB) * DIM + c16s * 8;

  float4 rA[2][8];

  for (int panel = pair; panel < 1032; panel += 128) {
    const size_t m0 = (size_t)panel * 128;
    const float* axp = x + (m0 + arow) * DIM + hs * 32;

    f32x4 acc[4][4];
#pragma unroll
    for (int mt = 0; mt < 4; ++mt)
#pragma unroll
      for (int nt = 0; nt < 4; ++nt) acc[mt][nt] = (f32x4){0.f, 0.f, 0.f, 0.f};

    auto issueB = [&](int j, int bsel) {
      char* dst = smem + 32768 + bsel * 16384 + t * 16;
#pragma unroll
      for (int u = 0; u < 4; ++u)
        gload_lds16(bsrc + (size_t)u * 32 * DIM + j * 64, dst + u * 4096);
    };
    auto issueA = [&](int j) {
      const float4* p = (const float4*)(axp + j * 64);
#pragma unroll
      for (int u = 0; u < 8; ++u) rA[j & 1][u] = p[u];
    };
    auto writeA = [&](int j) {
      char* dst = smem + (j & 1) * 16384 + arow * 128;
#pragma unroll
      for (int u = 0; u < 4; ++u) {
        float4 lo = rA[j & 1][2 * u], hi = rA[j & 1][2 * u + 1];
        short8 o;
        o[0] = (short)f2bf(lo.x); o[1] = (short)f2bf(lo.y);
        o[2] = (short)f2bf(lo.z); o[3] = (short)f2bf(lo.w);
        o[4] = (short)f2bf(hi.x); o[5] = (short)f2bf(hi.y);
        o[6] = (short)f2bf(hi.z); o[7] = (short)f2bf(hi.w);
        *(short8*)(dst + ((hs * 64 + u * 16) ^ asw)) = o;
      }
    };

    // prologue: B(0) staged, A(0) written, A(1) in flight
    issueB(0, 0);
    asm volatile("" ::: "memory");          // pin ordering: B-gloads oldest
    issueA(0);
    issueA(1);
    writeA(0);                               // compiler waits A(0) loads, leaves A(1)
    asm volatile("s_waitcnt vmcnt(8) lgkmcnt(0)" ::: "memory");  // B(0) drained, A(1) in flight
    __builtin_amdgcn_s_barrier();

#pragma unroll
    for (int kt = 0; kt < 8; ++kt) {
      if (kt < 7) issueB(kt + 1, (kt + 1) & 1);
      asm volatile("" ::: "memory");        // B-gloads older than following A loads
      if (kt < 6) issueA(kt + 2);
      asm volatile("" ::: "memory");
#pragma unroll
      for (int ks = 0; ks < 2; ++ks) {
        short8 am[4], bn[4];
#pragma unroll
        for (int mt = 0; mt < 4; ++mt)
          am[mt] = *(const short8*)(smem + (kt & 1) * 16384 +
                    (wm * 64 + mt * 16 + c) * 128 + ((ks * 64 + g * 16) ^ cs7));
#pragma unroll
        for (int nt = 0; nt < 4; ++nt)
          bn[nt] = *(const short8*)(smem + 32768 + (kt & 1) * 16384 +
                    (wn * 64 + nt * 16 + c) * 128 + ((ks * 64 + g * 16) ^ cs7));
#pragma unroll
        for (int mt = 0; mt < 4; ++mt)
#pragma unroll
          for (int nt = 0; nt < 4; ++nt)
            acc[mt][nt] = __builtin_amdgcn_mfma_f32_16x16x32_bf16(am[mt], bn[nt], acc[mt][nt], 0, 0, 0);
      }
      if (kt < 7) {
        writeA(kt + 1);                     // compiler waits A(kt+1), leaves B(kt+1)+A(kt+2)
        asm volatile("s_waitcnt vmcnt(8) lgkmcnt(0)" ::: "memory");
        __builtin_amdgcn_s_barrier();
      } else {
        __syncthreads();                    // full drain before epilogue
      }
    }

    // epilogue: 4 passes of 32 rows through Cs[32][128] (f32, XOR-swizzled)
#pragma unroll
    for (int p = 0; p < 4; ++p) {
      if (p) __syncthreads();               // prev pass reads done
      if (wm == (p >> 1)) {
        const int mtL = (p & 1) * 2;
#pragma unroll
        for (int mm = 0; mm < 2; ++mm)
#pragma unroll
          for (int nt = 0; nt < 4; ++nt)
#pragma unroll
            for (int r = 0; r < 4; ++r) {
              int lr = mm * 16 + 4 * g + r;
              int col4 = (wn * 64 + nt * 16 + c) * 4;
              *(float*)((char*)Cs + lr * 512 + (col4 ^ ((lr & 7) << 4))) = acc[mtL + mm][nt][r];
            }
      }
      __syncthreads();
      {
        const int lr = t >> 3, hh = (t >> 2) & 1, s = t & 3;
        const int mi = (int)m0 + p * 32 + lr;
        const int b = mi / NPOS, pos = mi % NPOS;
        const int base4 = hh * 256 + s * 32;
        const int sw = (lr & 7) << 4;
        const char* cb = (const char*)Cs + lr * 512;
        float4 a0 = *(const float4*)(cb + ((base4      ) ^ sw));
        float4 a1 = *(const float4*)(cb + ((base4 + 16 ) ^ sw));
        float4 b0 = *(const float4*)(cb + ((base4 + 128) ^ sw));
        float4 b1 = *(const float4*)(cb + ((base4 + 144) ^ sw));
        float v1[8] = {a0.x,a0.y,a0.z,a0.w,a1.x,a1.y,a1.z,a1.w};
        float v2[8] = {b0.x,b0.y,b0.z,b0.w,b1.x,b1.y,b1.z,b1.w};
        const float4* ct4 = (const float4*)(ctab + pos * 32 + s * 8);
        const float4* st4 = (const float4*)(stab + pos * 32 + s * 8);
        float4 c0 = ct4[0], c1 = ct4[1], s0 = st4[0], s1 = st4[1];
        float cc[8] = {c0.x,c0.y,c0.z,c0.w,c1.x,c1.y,c1.z,c1.w};
        float sn[8] = {s0.x,s0.y,s0.z,s0.w,s1.x,s1.y,s1.z,s1.w};
        float o1[8], o2[8];
        float sum = 0.f;
#pragma unroll
        for (int k = 0; k < 8; ++k) {
          float r1 = v1[k] * cc[k] - v2[k] * sn[k];
          float r2 = v2[k] * cc[k] + v1[k] * sn[k];
          o1[k] = r1; o2[k] = r2;
          sum += r1 + r2;
        }
        sum += __shfl_xor(sum, 1); sum += __shfl_xor(sum, 2);
        float mu = sum * 0.015625f;
        float sq = 0.f;                      // subtract-mean form (matches reference numerics)
#pragma unroll
        for (int k = 0; k < 8; ++k) {
          float d1 = o1[k] - mu, d2 = o2[k] - mu;
          sq = fmaf(d1, d1, fmaf(d2, d2, sq));
        }
        sq += __shfl_xor(sq, 1); sq += __shfl_xor(sq, 2);
        float rstd = rsqrtf(sq * 0.015625f + 1e-5f);
        int bh = b * 8 + (n0 >> 6) + hh;
        u16* kvp = kvws + ((size_t)bh * NPOS + pos) * DH;
        uint4 pk1, pk2;
        pk1.x = (u32)f2bf(o1[0]) | ((u32)f2bf(o1[1]) << 16);
        pk1.y = (u32)f2bf(o1[2]) | ((u32)f2bf(o1[3]) << 16);
        pk1.z = (u32)f2bf(o1[4]) | ((u32)f2bf(o1[5]) << 16);
        pk1.w = (u32)f2bf(o1[6]) | ((u32)f2bf(o1[7]) << 16);
        pk2.x = (u32)f2bf(o2[0]) | ((u32)f2bf(o2[1]) << 16);
        pk2.y = (u32)f2bf(o2[2]) | ((u32)f2bf(o2[3]) << 16);
        pk2.z = (u32)f2bf(o2[4]) | ((u32)f2bf(o2[5]) << 16);
        pk2.w = (u32)f2bf(o2[6]) | ((u32)f2bf(o2[7]) << 16);
        *(uint4*)(kvp + s * 8) = pk1;
        *(uint4*)(kvp + 32 + s * 8) = pk2;
        if (s == 0) stats[(size_t)bh * NPOS + pos] = make_float2(mu, rstd);
      }
    }
  }
}

// ---------------- kernel 3: flash attention, LN folded out of PV (4 chunks, validated R10) ----------------
// out_d = (g_d*(O_d - Q2) + b_d*L)/L with O = sum p*rstd*kv, Q2 = sum p*mu*rstd, L = sum p.
__global__ __launch_bounds__(256) void k_attn(
    const u16* __restrict__ qws, const u16* __restrict__ kvws,
    const float2* __restrict__ stats,
    float* __restrict__ pout, float* __restrict__ pml) {
  __shared__ __align__(16) u16 LT[64 * 64];        // raw kv^T [dd][j], rows XOR-swizzled
  __shared__ __align__(16) u16 Pl[4][16 * 64];     // per-wave P' [i][j], XOR-swizzled
  int t = threadIdx.x;
  int lane = t & 63, w = t >> 6;
  int c = lane & 15, g = lane >> 4;
  int bh = blockIdx.y, chunk = blockIdx.x;
  int tt0 = chunk * TPC;
  int tt1 = tt0 + TPC; if (tt1 > NTILES) tt1 = NTILES;
  short8 qa[2];
  {
    const u16* qrow = qws + ((size_t)bh * LAT + w * 16 + c) * DH;
    qa[0] = *(const short8*)(qrow + 8 * g);
    qa[1] = *(const short8*)(qrow + 32 + 8 * g);
  }
  f32x4 oacc[4];
#pragma unroll
  for (int nt = 0; nt < 4; ++nt) oacc[nt] = (f32x4){0.f, 0.f, 0.f, 0.f};
  float m_run[4], l_run[4], q2_run[4];
#pragma unroll
  for (int r = 0; r < 4; ++r) { m_run[r] = -INFINITY; l_run[r] = 0.f; q2_run[r] = 0.f; }
  int sj = t & 63, sw = t >> 6;
  for (int tt = tt0; tt < tt1; ++tt) {
    int j0 = tt * 64;
    __syncthreads();
    {                                               // pure transpose staging: LT[dd][j] = kv[j][dd]
      const u16* src = kvws + ((size_t)bh * NPOS + j0 + sj) * DH + 16 * sw;
      short8 v0 = *(const short8*)src;
      short8 v1 = *(const short8*)(src + 8);
      char* ltb = (char*)LT;
#pragma unroll
      for (int e = 0; e < 16; ++e) {
        int dd = 16 * sw + e;
        u16 uv = (u16)((e < 8) ? v0[e] : v1[e - 8]);
        *(u16*)(ltb + dd * 128 + ((2 * sj) ^ ((dd & 7) << 4))) = uv;
      }
    }
    __syncthreads();
    f32x4 sacc[4];
#pragma unroll
    for (int jn = 0; jn < 4; ++jn) sacc[jn] = (f32x4){0.f, 0.f, 0.f, 0.f};
    const u16* kb = kvws + ((size_t)bh * NPOS + j0) * DH;
#pragma unroll
    for (int ks = 0; ks < 2; ++ks)
#pragma unroll
      for (int jn = 0; jn < 4; ++jn) {
        short8 kf = *(const short8*)(kb + (size_t)(jn * 16 + c) * DH + ks * 32 + 8 * g);
        sacc[jn] = __builtin_amdgcn_mfma_f32_16x16x32_bf16(qa[ks], kf, sacc[jn], 0, 0, 0);
      }
    float rsd[4], musig[4];
#pragma unroll
    for (int jn = 0; jn < 4; ++jn) {
      float2 sv = stats[(size_t)bh * NPOS + j0 + jn * 16 + c];
      rsd[jn] = sv.y; musig[jn] = sv.x * sv.y;
    }
    char* pb = (char*)Pl[w];
#pragma unroll
    for (int r = 0; r < 4; ++r) {
      float mt0 = fmaxf(fmaxf(sacc[0][r], sacc[1][r]), fmaxf(sacc[2][r], sacc[3][r]));
      mt0 = fmaxf(mt0, __shfl_xor(mt0, 1));
      mt0 = fmaxf(mt0, __shfl_xor(mt0, 2));
      mt0 = fmaxf(mt0, __shfl_xor(mt0, 4));
      mt0 = fmaxf(mt0, __shfl_xor(mt0, 8));
      float mnew = fmaxf(m_run[r], mt0);
      float corr = __expf(m_run[r] - mnew);
      m_run[r] = mnew;
      float ts = 0.f, tq = 0.f;
#pragma unroll
      for (int jn = 0; jn < 4; ++jn) {
        float p = __expf(sacc[jn][r] - mnew);
        ts += p;
        tq = fmaf(p, musig[jn], tq);
        sacc[jn][r] = p * rsd[jn];              // P' = p * rstd_j
      }
      ts += __shfl_xor(ts, 1); ts += __shfl_xor(ts, 2);
      ts += __shfl_xor(ts, 4); ts += __shfl_xor(ts, 8);
      tq += __shfl_xor(tq, 1); tq += __shfl_xor(tq, 2);
      tq += __shfl_xor(tq, 4); tq += __shfl_xor(tq, 8);
      l_run[r]  = l_run[r]  * corr + ts;
      q2_run[r] = q2_run[r] * corr + tq;
#pragma unroll
      for (int nt = 0; nt < 4; ++nt) oacc[nt][r] *= corr;
      int i = 4 * g + r;
      int isw = (i & 7) << 4;
#pragma unroll
      for (int jn = 0; jn < 4; ++jn) {
        int j = jn * 16 + c;
        *(u16*)(pb + i * 128 + ((2 * j) ^ isw)) = f2bf(sacc[jn][r]);
      }
    }
#pragma unroll
    for (int ks = 0; ks < 2; ++ks) {
      short8 pa = *(const short8*)(pb + c * 128 + ((ks * 64 + 16 * g) ^ ((c & 7) << 4)));
#pragma unroll
      for (int nt = 0; nt < 4; ++nt) {
        int dd = nt * 16 + c;
        short8 lv = *(const short8*)((char*)LT + dd * 128 + ((ks * 64 + 16 * g) ^ ((dd & 7) << 4)));
        oacc[nt] = __builtin_amdgcn_mfma_f32_16x16x32_bf16(pa, lv, oacc[nt], 0, 0, 0);
      }
    }
  }
  size_t ob = (size_t)bh * NCHUNK + chunk;
#pragma unroll
  for (int nt = 0; nt < 4; ++nt)
#pragma unroll
    for (int r = 0; r < 4; ++r) {
      int i = w * 16 + 4 * g + r;
      pout[(ob * 64 + i) * 64 + nt * 16 + c] = oacc[nt][r];
    }
  if (c == 0) {
#pragma unroll
    for (int r = 0; r < 4; ++r) {
      int i = w * 16 + 4 * g + r;
      pml[(ob * 3 + 0) * 64 + i] = m_run[r];
      pml[(ob * 3 + 1) * 64 + i] = l_run[r];
      pml[(ob * 3 + 2) * 64 + i] = q2_run[r];
    }
  }
}

// ---------------- kernel 4: combine chunks, apply LN gamma/beta, permute to output ----------------
__global__ __launch_bounds__(256) void k_combine(
    const float* __restrict__ pout, const float* __restrict__ pml,
    const float* __restrict__ lng, const float* __restrict__ lnb,
    float* __restrict__ out) {
  int bh = blockIdx.x, t = threadIdx.x;
  int i = t >> 2, dq = t & 3;
  float mv[NCHUNK], lv[NCHUNK], qv[NCHUNK];
#pragma unroll
  for (int cc = 0; cc < NCHUNK; ++cc) {
    size_t ob = (size_t)bh * NCHUNK + cc;
    mv[cc] = pml[(ob * 3 + 0) * 64 + i];
    lv[cc] = pml[(ob * 3 + 1) * 64 + i];
    qv[cc] = pml[(ob * 3 + 2) * 64 + i];
  }
  float M = -INFINITY;
#pragma unroll
  for (int cc = 0; cc < NCHUNK; ++cc) M = fmaxf(M, mv[cc]);
  float L = 0.f, Q2 = 0.f, wcf[NCHUNK];
#pragma unroll
  for (int cc = 0; cc < NCHUNK; ++cc) {
    wcf[cc] = __expf(mv[cc] - M);
    L = fmaf(wcf[cc], lv[cc], L);
    Q2 = fmaf(wcf[cc], qv[cc], Q2);
  }
  float invL = 1.0f / L;
#pragma unroll
  for (int e = 0; e < 16; ++e) {
    int dd = dq * 16 + e;
    float O = 0.f;
#pragma unroll
    for (int cc = 0; cc < NCHUNK; ++cc)
      O = fmaf(wcf[cc], pout[(((size_t)bh * NCHUNK + cc) * 64 + i) * 64 + dd], O);
    float val = (lng[dd] * (O - Q2) + lnb[dd] * L) * invL;
    out[((size_t)(bh >> 3) * LAT + i) * DIM + (bh & 7) * DH + dd] = val;
  }
}

extern "C" void kernel_launch(void* const* d_in, const int* in_sizes, int n_in,
                              void* d_out, int out_size, void* d_ws, size_t ws_size,
                              hipStream_t stream) {
  const float* x   = (const float*)d_in[0];
  const float* wq  = (const float*)d_in[1];
  const float* wkv = (const float*)d_in[2];
  const float* lng = (const float*)d_in[3];
  const float* lnb = (const float*)d_in[4];
  float* out = (float*)d_out;
  char* ws = (char*)d_ws;
  size_t off = 0;
  auto alloc = [&](size_t bytes) { char* p = ws + off; off += (bytes + 255) & ~(size_t)255; return p; };
  float*  ctab  = (float*)alloc((size_t)NPOS * 32 * 4);
  float*  stab  = (float*)alloc((size_t)NPOS * 32 * 4);
  u16*    qws   = (u16*)alloc((size_t)NBH * LAT * DH * 2);
  u16*    kvws  = (u16*)alloc((size_t)NBH * NPOS * DH * 2);
  float2* stats = (float2*)alloc((size_t)NBH * NPOS * 8);
  float*  pout  = (float*)alloc((size_t)NBH * NCHUNK * 64 * 64 * 4);
  float*  pml   = (float*)alloc((size_t)NBH * NCHUNK * 3 * 64 * 4);
  u16*    wbf   = (u16*)alloc((size_t)DIM * DIM * 2);
  (void)in_sizes; (void)n_in; (void)out_size; (void)ws_size;

  hipLaunchKernelGGL(k_rtable, dim3(NPOS * 32 / 256), dim3(256), 0, stream, ctab, stab);
  hipLaunchKernelGGL(k_wcast, dim3(DIM * DIM / 8 / 256), dim3(256), 0, stream, wkv, wbf);
  hipLaunchKernelGGL(k_qproj, dim3(128), dim3(256), 0, stream, x, wq, ctab, stab, qws);
  hipLaunchKernelGGL(k_kvgemm, dim3(512), dim3(256), 0, stream, x, wbf, ctab, stab, kvws, stats);
  hipLaunchKernelGGL(k_attn, dim3(NCHUNK, NBH), dim3(256), 0, stream, qws, kvws, stats, pout, pml);
  hipLaunchKernelGGL(k_combine, dim3(NBH), dim3(256), 0, stream, pout, pml, lng, lnb, out);
}